// Round 2
// baseline (1017.972 us; speedup 1.0000x reference)
//
#include <hip/hip_runtime.h>
#include <math.h>

#define ROWS 32768
#define COLS 1024
#define HEADSZ 1030      // COLS + 1 + 1 + 3 + 1
#define NPARAMS 4108     // 2*HEADSZ + 2*COLS
#define NBLK 1024        // 4 blocks/CU * 256 CUs (exact-fit, enforced by launch_bounds)
#define SLOT_E 32        // slotted accumulators, cache-line padded (stride 16 floats)
#define SLOT_P 16
// barrier layout (ints, within ws): group g counter at [g*16] (32 groups),
// root counter at [512], generation at [528]; total 544 ints
#define BAR_ROOT 512
#define BAR_GEN  528
#define BAR_INTS 544

typedef float vfloat4 __attribute__((ext_vector_type(4)));

struct KArgs {
    const float *x, *rp, *Wc, *bc, *Wp, *bp, *Wo, *bo, *wrp, *wwp, *mem;
    float *h, *p, *saida, *krn, *kwn, *evec, *avec, *scal, *sumsEs, *sumsPs;
    int   *bar;
    float *er, *ew, *partials, *memnew, *readv, *owr, *oww;
};

__device__ __forceinline__ float softplusf(float x) {
    return fmaxf(x, 0.f) + log1pf(expf(-fabsf(x)));
}
__device__ __forceinline__ float sigmoidf(float x) {
    return 1.f / (1.f + expf(-x));
}
__device__ __forceinline__ float waveReduceSum(float v) {
#pragma unroll
    for (int off = 32; off > 0; off >>= 1) v += __shfl_xor(v, off, 64);
    return v;
}

// Tree grid barrier in workspace: release-fence -> arrive (group, then root),
// last root arriver bumps generation; everyone else acquire-spins on it.
// Agent-scope atomics + __threadfence handle cross-XCD L2 visibility.
__device__ __forceinline__ void gridBar(int* bar, int bid) {
    __syncthreads();
    if (threadIdx.x == 0) {
        __threadfence();  // release: make this block's stores device-visible
        int* gen = bar + BAR_GEN;
        int g = __hip_atomic_load(gen, __ATOMIC_RELAXED, __HIP_MEMORY_SCOPE_AGENT);
        bool released = false;
        int grp = bid >> 5;
        if (__hip_atomic_fetch_add(bar + grp * 16, 1, __ATOMIC_ACQ_REL,
                                   __HIP_MEMORY_SCOPE_AGENT) == 31) {
            __hip_atomic_store(bar + grp * 16, 0, __ATOMIC_RELAXED,
                               __HIP_MEMORY_SCOPE_AGENT);
            if (__hip_atomic_fetch_add(bar + BAR_ROOT, 1, __ATOMIC_ACQ_REL,
                                       __HIP_MEMORY_SCOPE_AGENT) == (NBLK >> 5) - 1) {
                __hip_atomic_store(bar + BAR_ROOT, 0, __ATOMIC_RELAXED,
                                   __HIP_MEMORY_SCOPE_AGENT);
                __hip_atomic_fetch_add(gen, 1, __ATOMIC_RELEASE,
                                       __HIP_MEMORY_SCOPE_AGENT);
                released = true;
            }
        }
        if (!released) {
            int it = 0;
            while (__hip_atomic_load(gen, __ATOMIC_ACQUIRE,
                                     __HIP_MEMORY_SCOPE_AGENT) == g) {
                __builtin_amdgcn_s_sleep(8);
                if (++it > (1 << 18)) break;  // safety valve: never hang the queue
            }
        }
        __threadfence();  // acquire: invalidate stale cached lines
    }
    __syncthreads();
}

// one output of p/saida: full-1024 dot by one wave
__device__ __forceinline__ void dotOut(const KArgs& A, const float* hl, int o, int lane) {
    bool isP = o < NPARAMS;
    int oo = isP ? o : o - NPARAMS;
    const float* W = isP ? A.Wp : A.Wo;
    const float4* Wr = (const float4*)(W + (size_t)oo * 1024);
    float acc = 0.f;
#pragma unroll
    for (int j = 0; j < 4; j++) {
        float4 w = Wr[lane + 64 * j];
        float4 v = *(const float4*)(hl + lane * 4 + j * 256);
        acc += w.x * v.x + w.y * v.y + w.z * v.z + w.w * v.w;
    }
    acc = waveReduceSum(acc);
    if (lane == 0) {
        if (isP) A.p[oo] = acc + A.bp[oo];
        else     A.saida[oo] = sigmoidf(acc + A.bo[oo]);
    }
}

// zero barrier state + slotted accumulators + readv (ws is poisoned each launch)
__global__ __launch_bounds__(256) void kInit(int* bar, float* sumsEs,
                                             float* sumsPs, float* readv) {
    int t = threadIdx.x;
    for (int i = t; i < BAR_INTS; i += 256) bar[i] = 0;
    for (int i = t; i < 1024; i += 256) { sumsEs[i] = 0.f; readv[i] = 0.f; }
    for (int i = t; i < 512; i += 256) sumsPs[i] = 0.f;
}

__global__ __launch_bounds__(256, 4) void mega(KArgs A) {
    const int b = blockIdx.x, t = threadIdx.x;
    const int w = t >> 6, lane = t & 63;
    __shared__ float sbuf[1280];   // phase 0: xc, phase 1: h, phase 2: reduction
    __shared__ float spw[64];      // persistent: sharpened weights for this block's 32 rows
    __shared__ float sred[8];

    // ---- phase 0 (kA): h = Wc @ concat(x, read_prev) + bc  (blocks 0..255)
    if (b < 256) {
        for (int i = t; i < 1280; i += 256) sbuf[i] = (i < 256) ? A.x[i] : A.rp[i - 256];
        __syncthreads();
        int o = b * 4 + w;
        const float4* Wr = (const float4*)(A.Wc + (size_t)o * 1280);
        float acc = 0.f;
#pragma unroll
        for (int j = 0; j < 5; j++) {
            float4 wv = Wr[lane + 64 * j];
            float4 v = *(const float4*)(sbuf + lane * 4 + j * 256);
            acc += wv.x * v.x + wv.y * v.y + wv.z * v.z + wv.w * v.w;
        }
        acc = waveReduceSum(acc);
        if (lane == 0) A.h[o] = acc + A.bc[o];
    }
    gridBar(A.bar, b);

    // ---- phase 1 (kB): 4364 outputs = 1024 blocks * 4 (+ blocks<67 do 4 more)
    {
        for (int i = t; i < 1024; i += 256) sbuf[i] = A.h[i];
        __syncthreads();
        dotOut(A, sbuf, b * 4 + w, lane);
        if (b < 67) dotOut(A, sbuf, 4096 + b * 4 + w, lane);
    }
    gridBar(A.bar, b);

    // ---- phase 2 (kC): normalized keys, e/a vectors, scalar params
    if (b < 2) {
        const float* pk = A.p + (b ? HEADSZ : 0);
        float tr[4], ss = 0.f;
#pragma unroll
        for (int j = 0; j < 4; j++) { tr[j] = tanhf(pk[t + 256 * j]); ss += tr[j] * tr[j]; }
        sbuf[t] = ss;
        __syncthreads();
        for (int s2 = 128; s2 > 0; s2 >>= 1) {
            if (t < s2) sbuf[t] += sbuf[t + s2];
            __syncthreads();
        }
        float inv = 1.f / fmaxf(sqrtf(sbuf[0]), 1e-12f);
        float* kd = b ? A.kwn : A.krn;
#pragma unroll
        for (int j = 0; j < 4; j++) kd[t + 256 * j] = tr[j] * inv;
    } else if (b == 2) {
#pragma unroll
        for (int j = 0; j < 4; j++) {
            int i = t + 256 * j;
            A.evec[i] = sigmoidf(A.p[2 * HEADSZ + i]);
            A.avec[i] = tanhf(A.p[2 * HEADSZ + COLS + i]);
        }
    } else if (b == 3 && t < 2) {
        int base = t * HEADSZ + COLS;            // 1024 (read) / 2054 (write)
        float beta = softplusf(A.p[base]);
        float g = sigmoidf(A.p[base + 1]);
        float s0 = A.p[base + 2], s1 = A.p[base + 3], s2 = A.p[base + 4];
        float mx = fmaxf(s0, fmaxf(s1, s2));
        float e0 = expf(s0 - mx), e1 = expf(s1 - mx), e2 = expf(s2 - mx);
        float invs = 1.f / (e0 + e1 + e2);
        float gamma = softplusf(A.p[base + 5]) + 1.f;
        float* sc = A.scal + t * 6;
        sc[0] = beta; sc[1] = g;
        sc[2] = e0 * invs; sc[3] = e1 * invs; sc[4] = e2 * invs;
        sc[5] = gamma;
    }
    gridBar(A.bar, b);

    // ---- phase 3 (kD): sims + row norms -> exp terms + slotted sums (32 rows/block)
    {
        const float beta_r = A.scal[0], beta_w = A.scal[6];
        float4 kr4[4], kw4[4];
#pragma unroll
        for (int j = 0; j < 4; j++) {
            kr4[j] = ((const float4*)A.krn)[lane + 64 * j];
            kw4[j] = ((const float4*)A.kwn)[lane + 64 * j];
        }
        float lr = 0.f, lw = 0.f;
#pragma unroll
        for (int rr = 0; rr < 8; rr++) {
            int r = b * 32 + w * 8 + rr;
            const float4* row = (const float4*)(A.mem + (size_t)r * COLS);
            float ar = 0.f, aw = 0.f, an = 0.f;
#pragma unroll
            for (int j = 0; j < 4; j++) {
                float4 m = row[lane + 64 * j];
                ar += m.x * kr4[j].x + m.y * kr4[j].y + m.z * kr4[j].z + m.w * kr4[j].w;
                aw += m.x * kw4[j].x + m.y * kw4[j].y + m.z * kw4[j].z + m.w * kw4[j].w;
                an += m.x * m.x + m.y * m.y + m.z * m.z + m.w * m.w;
            }
#pragma unroll
            for (int off = 32; off > 0; off >>= 1) {
                ar += __shfl_xor(ar, off, 64);
                aw += __shfl_xor(aw, off, 64);
                an += __shfl_xor(an, off, 64);
            }
            if (lane == 0) {
                float inv = 1.f / fmaxf(sqrtf(an), 1e-12f);
                // softmax shift by beta (max(beta*sim) <= beta) — exact math
                float vr = expf(beta_r * (ar * inv - 1.f));
                float vw = expf(beta_w * (aw * inv - 1.f));
                A.er[r] = vr; A.ew[r] = vw;
                lr += vr; lw += vw;
            }
        }
        if (lane == 0) { sred[w] = lr; sred[4 + w] = lw; }
        __syncthreads();
        if (t == 0) {
            int slot = b & (SLOT_E - 1);
            atomicAdd(&A.sumsEs[slot * 16], sred[0] + sred[1] + sred[2] + sred[3]);
            atomicAdd(&A.sumsEs[(SLOT_E + slot) * 16], sred[4] + sred[5] + sred[6] + sred[7]);
        }
    }
    gridBar(A.bar, b);

    // ---- phase 4 (kE): gate + circular shift + sharpen for this block's 32 rows
    if (t < 64) {
        int head = t >> 5, rr = t & 31;
        int i = b * 32 + rr;
        const float* ee = head ? A.ew : A.er;
        const float* wp = head ? A.wwp : A.wrp;
        const float* sc = A.scal + head * 6;
        float g = sc[1], s0 = sc[2], s1 = sc[3], s2 = sc[4], gamma = sc[5];
        float sE = 0.f;
#pragma unroll
        for (int k = 0; k < SLOT_E; k++) sE += A.sumsEs[(head * SLOT_E + k) * 16];
        float invS = 1.f / sE;
        int im = (i - 1) & (ROWS - 1), ip = (i + 1) & (ROWS - 1);
        float wgm = g * ee[im] * invS + (1.f - g) * wp[im];
        float wg0 = g * ee[i]  * invS + (1.f - g) * wp[i];
        float wgp = g * ee[ip] * invS + (1.f - g) * wp[ip];
        float wt = s0 * wgm + s1 * wg0 + s2 * wgp;
        float pw = powf(wt, gamma);
        spw[t] = pw;                      // stays in LDS for phase 5
        float v = pw;
#pragma unroll
        for (int off = 16; off > 0; off >>= 1) v += __shfl_xor(v, off, 64); // 32-half sums
        if (rr == 0) atomicAdd(&A.sumsPs[(head * SLOT_P + (b & (SLOT_P - 1))) * 16], v);
    }
    gridBar(A.bar, b);

    // ---- phase 5 (kG): normalize, write w_read/w_write, erase+add, read_vec partials
    {
        int r0 = b * 32;
        if (t < 64) {
            int head = t >> 5;
            float s = 0.f;
#pragma unroll
            for (int k = 0; k < SLOT_P; k++) s += A.sumsPs[(head * SLOT_P + k) * 16];
            float inv = 1.f / (s + 1e-8f);
            float vv = spw[t] * inv;
            spw[t] = vv;
            if (head == 0) A.owr[r0 + t] = vv;
            else           A.oww[r0 + (t - 32)] = vv;
        }
        __syncthreads();
        float4 e4 = ((const float4*)A.evec)[t];
        float4 a4 = ((const float4*)A.avec)[t];
        float4 acc = make_float4(0.f, 0.f, 0.f, 0.f);
#pragma unroll 4
        for (int rr = 0; rr < 32; rr++) {
            int r = r0 + rr;
            float wr = spw[rr], ww = spw[32 + rr];
            float4 m = ((const float4*)(A.mem + (size_t)r * COLS))[t];
            vfloat4 o;
            o.x = m.x * (1.f - ww * e4.x) + ww * a4.x;
            o.y = m.y * (1.f - ww * e4.y) + ww * a4.y;
            o.z = m.z * (1.f - ww * e4.z) + ww * a4.z;
            o.w = m.w * (1.f - ww * e4.w) + ww * a4.w;
            __builtin_nontemporal_store(o, ((vfloat4*)(A.memnew + (size_t)r * COLS)) + t);
            acc.x += wr * m.x; acc.y += wr * m.y; acc.z += wr * m.z; acc.w += wr * m.w;
        }
        ((float4*)(A.partials + (size_t)b * COLS))[t] = acc;
    }
    gridBar(A.bar, b);

    // ---- phase 6 (kH): coalesced split-k reduce of partials into readv
    if (b < 128) {
        int ks = b >> 2;                 // 32 k-chunks of 32 partial-blocks each
        int c = (b & 3) * 256 + t;       // consecutive threads -> consecutive columns
        float s = 0.f;
#pragma unroll 8
        for (int k = 0; k < 32; k++) s += A.partials[(size_t)(ks * 32 + k) * COLS + c];
        atomicAdd(&A.readv[c], s);       // 32 adds per column, readv zeroed by kInit
    }
}

extern "C" void kernel_launch(void* const* d_in, const int* in_sizes, int n_in,
                              void* d_out, int out_size, void* d_ws, size_t ws_size,
                              hipStream_t stream) {
    const float* x   = (const float*)d_in[0];
    const float* mem = (const float*)d_in[1];
    const float* Wc  = (const float*)d_in[2];
    const float* bc  = (const float*)d_in[3];
    const float* Wp  = (const float*)d_in[4];
    const float* bp  = (const float*)d_in[5];
    const float* Wo  = (const float*)d_in[6];
    const float* bo  = (const float*)d_in[7];
    const float* rp  = (const float*)d_in[8];
    const float* wrp = (const float*)d_in[9];
    const float* wwp = (const float*)d_in[10];

    float* out    = (float*)d_out;
    float* saida  = out;                                // 256
    float* memnew = out + 256;                          // ROWS*COLS
    float* readv  = out + 256 + (size_t)ROWS * COLS;    // 1024
    float* owr    = readv + COLS;                       // 32768
    float* oww    = owr + ROWS;                         // 32768

    float* ws     = (float*)d_ws;
    float* h      = ws;             // 1024
    float* p      = ws + 1024;      // 4108 (padded)
    float* krn    = ws + 5136;      // 1024
    float* kwn    = ws + 6160;      // 1024
    float* evec   = ws + 7184;      // 1024
    float* avec   = ws + 8208;      // 1024
    float* scal   = ws + 9232;      // 12 (padded to 16)
    float* sumsEs = ws + 9248;      // 2*SLOT_E*16 = 1024
    float* sumsPs = ws + 10272;     // 2*SLOT_P*16 = 512
    int*   bar    = (int*)(ws + 10784);  // 544 ints (padded to 560)
    float* er     = ws + 11344;     // 32768
    float* ew     = er + ROWS;      // 32768
    float* partials = ew + ROWS;    // NBLK*COLS = 1M floats (4 MB)

    KArgs A;
    A.x = x; A.rp = rp; A.Wc = Wc; A.bc = bc; A.Wp = Wp; A.bp = bp;
    A.Wo = Wo; A.bo = bo; A.wrp = wrp; A.wwp = wwp; A.mem = mem;
    A.h = h; A.p = p; A.saida = saida; A.krn = krn; A.kwn = kwn;
    A.evec = evec; A.avec = avec; A.scal = scal; A.sumsEs = sumsEs;
    A.sumsPs = sumsPs; A.bar = bar; A.er = er; A.ew = ew; A.partials = partials;
    A.memnew = memnew; A.readv = readv; A.owr = owr; A.oww = oww;

    kInit<<<dim3(1), dim3(256), 0, stream>>>(bar, sumsEs, sumsPs, readv);
    mega<<<dim3(NBLK), dim3(256), 0, stream>>>(A);
}

// Round 3
// 682.548 us; speedup vs baseline: 1.4914x; 1.4914x over previous
//
#include <hip/hip_runtime.h>
#include <math.h>

#define ROWS 32768
#define COLS 1024
#define HEADSZ 1030      // COLS + 1 + 1 + 3 + 1
#define NPARAMS 4108     // 2*HEADSZ + 2*COLS
#define NBLK 1024        // 4 blocks/CU * 256 CUs (exact-fit, enforced by launch_bounds)
#define SLOT_E 32        // slotted accumulators, cache-line padded (stride 16 floats)
#define SLOT_P 16
// barrier layout (ints, within ws): group g counter at [g*16] (32 groups),
// root counter at [512], generation at [528]; total 544 ints
#define BAR_ROOT 512
#define BAR_GEN  528
#define BAR_INTS 544

typedef float vfloat4 __attribute__((ext_vector_type(4)));

struct KArgs {
    const float *x, *rp, *Wc, *bc, *Wp, *bp, *Wo, *bo, *wrp, *wwp, *mem;
    float *h, *p, *saida, *krn, *kwn, *evec, *avec, *scal, *sumsEs, *sumsPs;
    int   *bar;
    float *er, *ew, *partials, *memnew, *readv, *owr, *oww;
};

__device__ __forceinline__ float softplusf(float x) {
    return fmaxf(x, 0.f) + log1pf(expf(-fabsf(x)));
}
__device__ __forceinline__ float sigmoidf(float x) {
    return 1.f / (1.f + expf(-x));
}
__device__ __forceinline__ float waveReduceSum(float v) {
#pragma unroll
    for (int off = 32; off > 0; off >>= 1) v += __shfl_xor(v, off, 64);
    return v;
}

// Tree grid barrier in workspace.
// CRITICAL: the spin polls with RELAXED loads (plain coherent-point read).
// An ACQUIRE load at agent scope emits buffer_inv (L2 invalidate) per poll —
// a grid-wide cache-maintenance storm that measured 850 µs in round 2.
// Visibility is instead established ONCE at exit via __threadfence().
__device__ __forceinline__ void gridBar(int* bar, int bid) {
    __syncthreads();
    if (threadIdx.x == 0) {
        __threadfence();  // release: make this block's stores device-visible
        int* gen = bar + BAR_GEN;
        int g = __hip_atomic_load(gen, __ATOMIC_RELAXED, __HIP_MEMORY_SCOPE_AGENT);
        bool released = false;
        int grp = bid >> 5;
        if (__hip_atomic_fetch_add(bar + grp * 16, 1, __ATOMIC_ACQ_REL,
                                   __HIP_MEMORY_SCOPE_AGENT) == 31) {
            __hip_atomic_store(bar + grp * 16, 0, __ATOMIC_RELAXED,
                               __HIP_MEMORY_SCOPE_AGENT);
            if (__hip_atomic_fetch_add(bar + BAR_ROOT, 1, __ATOMIC_ACQ_REL,
                                       __HIP_MEMORY_SCOPE_AGENT) == (NBLK >> 5) - 1) {
                __hip_atomic_store(bar + BAR_ROOT, 0, __ATOMIC_RELAXED,
                                   __HIP_MEMORY_SCOPE_AGENT);
                __hip_atomic_fetch_add(gen, 1, __ATOMIC_RELEASE,
                                       __HIP_MEMORY_SCOPE_AGENT);
                released = true;
            }
        }
        if (!released) {
            int it = 0;
            while (__hip_atomic_load(gen, __ATOMIC_RELAXED,
                                     __HIP_MEMORY_SCOPE_AGENT) == g) {
                __builtin_amdgcn_s_sleep(8);
                if (++it > (1 << 18)) break;  // safety valve: never hang the queue
            }
        }
        __threadfence();  // acquire: single L2 invalidate before reading peers' data
    }
    __syncthreads();
}

// one output of p/saida: full-1024 dot by one wave
__device__ __forceinline__ void dotOut(const KArgs& A, const float* hl, int o, int lane) {
    bool isP = o < NPARAMS;
    int oo = isP ? o : o - NPARAMS;
    const float* W = isP ? A.Wp : A.Wo;
    const float4* Wr = (const float4*)(W + (size_t)oo * 1024);
    float acc = 0.f;
#pragma unroll
    for (int j = 0; j < 4; j++) {
        float4 w = Wr[lane + 64 * j];
        float4 v = *(const float4*)(hl + lane * 4 + j * 256);
        acc += w.x * v.x + w.y * v.y + w.z * v.z + w.w * v.w;
    }
    acc = waveReduceSum(acc);
    if (lane == 0) {
        if (isP) A.p[oo] = acc + A.bp[oo];
        else     A.saida[oo] = sigmoidf(acc + A.bo[oo]);
    }
}

// zero barrier state + slotted accumulators + readv (ws is poisoned each launch)
__global__ __launch_bounds__(256) void kInit(int* bar, float* sumsEs,
                                             float* sumsPs, float* readv) {
    int t = threadIdx.x;
    for (int i = t; i < BAR_INTS; i += 256) bar[i] = 0;
    for (int i = t; i < 1024; i += 256) { sumsEs[i] = 0.f; readv[i] = 0.f; }
    for (int i = t; i < 512; i += 256) sumsPs[i] = 0.f;
}

__global__ __launch_bounds__(256, 4) void mega(KArgs A) {
    const int b = blockIdx.x, t = threadIdx.x;
    const int w = t >> 6, lane = t & 63;
    __shared__ float sbuf[1280];   // phase 0: xc, phase 1: h, phase 2: reduction
    __shared__ float spw[64];      // persistent: sharpened weights for this block's 32 rows
    __shared__ float sred[8];

    // ---- phase 0 (kA): h = Wc @ concat(x, read_prev) + bc  (blocks 0..255)
    if (b < 256) {
        for (int i = t; i < 1280; i += 256) sbuf[i] = (i < 256) ? A.x[i] : A.rp[i - 256];
        __syncthreads();
        int o = b * 4 + w;
        const float4* Wr = (const float4*)(A.Wc + (size_t)o * 1280);
        float acc = 0.f;
#pragma unroll
        for (int j = 0; j < 5; j++) {
            float4 wv = Wr[lane + 64 * j];
            float4 v = *(const float4*)(sbuf + lane * 4 + j * 256);
            acc += wv.x * v.x + wv.y * v.y + wv.z * v.z + wv.w * v.w;
        }
        acc = waveReduceSum(acc);
        if (lane == 0) A.h[o] = acc + A.bc[o];
    }
    gridBar(A.bar, b);

    // ---- phase 1 (kB): 4364 outputs = 1024 blocks * 4 (+ blocks<67 do 4 more)
    {
        for (int i = t; i < 1024; i += 256) sbuf[i] = A.h[i];
        __syncthreads();
        dotOut(A, sbuf, b * 4 + w, lane);
        if (b < 67) dotOut(A, sbuf, 4096 + b * 4 + w, lane);
    }
    gridBar(A.bar, b);

    // ---- phase 2 (kC): normalized keys, e/a vectors, scalar params
    if (b < 2) {
        const float* pk = A.p + (b ? HEADSZ : 0);
        float tr[4], ss = 0.f;
#pragma unroll
        for (int j = 0; j < 4; j++) { tr[j] = tanhf(pk[t + 256 * j]); ss += tr[j] * tr[j]; }
        sbuf[t] = ss;
        __syncthreads();
        for (int s2 = 128; s2 > 0; s2 >>= 1) {
            if (t < s2) sbuf[t] += sbuf[t + s2];
            __syncthreads();
        }
        float inv = 1.f / fmaxf(sqrtf(sbuf[0]), 1e-12f);
        float* kd = b ? A.kwn : A.krn;
#pragma unroll
        for (int j = 0; j < 4; j++) kd[t + 256 * j] = tr[j] * inv;
    } else if (b == 2) {
#pragma unroll
        for (int j = 0; j < 4; j++) {
            int i = t + 256 * j;
            A.evec[i] = sigmoidf(A.p[2 * HEADSZ + i]);
            A.avec[i] = tanhf(A.p[2 * HEADSZ + COLS + i]);
        }
    } else if (b == 3 && t < 2) {
        int base = t * HEADSZ + COLS;            // 1024 (read) / 2054 (write)
        float beta = softplusf(A.p[base]);
        float g = sigmoidf(A.p[base + 1]);
        float s0 = A.p[base + 2], s1 = A.p[base + 3], s2 = A.p[base + 4];
        float mx = fmaxf(s0, fmaxf(s1, s2));
        float e0 = expf(s0 - mx), e1 = expf(s1 - mx), e2 = expf(s2 - mx);
        float invs = 1.f / (e0 + e1 + e2);
        float gamma = softplusf(A.p[base + 5]) + 1.f;
        float* sc = A.scal + t * 6;
        sc[0] = beta; sc[1] = g;
        sc[2] = e0 * invs; sc[3] = e1 * invs; sc[4] = e2 * invs;
        sc[5] = gamma;
    }
    gridBar(A.bar, b);

    // ---- phase 3 (kD): sims + row norms -> exp terms + slotted sums (32 rows/block)
    {
        const float beta_r = A.scal[0], beta_w = A.scal[6];
        float4 kr4[4], kw4[4];
#pragma unroll
        for (int j = 0; j < 4; j++) {
            kr4[j] = ((const float4*)A.krn)[lane + 64 * j];
            kw4[j] = ((const float4*)A.kwn)[lane + 64 * j];
        }
        float lr = 0.f, lw = 0.f;
#pragma unroll
        for (int rr = 0; rr < 8; rr++) {
            int r = b * 32 + w * 8 + rr;
            const float4* row = (const float4*)(A.mem + (size_t)r * COLS);
            float ar = 0.f, aw = 0.f, an = 0.f;
#pragma unroll
            for (int j = 0; j < 4; j++) {
                float4 m = row[lane + 64 * j];
                ar += m.x * kr4[j].x + m.y * kr4[j].y + m.z * kr4[j].z + m.w * kr4[j].w;
                aw += m.x * kw4[j].x + m.y * kw4[j].y + m.z * kw4[j].z + m.w * kw4[j].w;
                an += m.x * m.x + m.y * m.y + m.z * m.z + m.w * m.w;
            }
#pragma unroll
            for (int off = 32; off > 0; off >>= 1) {
                ar += __shfl_xor(ar, off, 64);
                aw += __shfl_xor(aw, off, 64);
                an += __shfl_xor(an, off, 64);
            }
            if (lane == 0) {
                float inv = 1.f / fmaxf(sqrtf(an), 1e-12f);
                // softmax shift by beta (max(beta*sim) <= beta) — exact math
                float vr = expf(beta_r * (ar * inv - 1.f));
                float vw = expf(beta_w * (aw * inv - 1.f));
                A.er[r] = vr; A.ew[r] = vw;
                lr += vr; lw += vw;
            }
        }
        if (lane == 0) { sred[w] = lr; sred[4 + w] = lw; }
        __syncthreads();
        if (t == 0) {
            int slot = b & (SLOT_E - 1);
            atomicAdd(&A.sumsEs[slot * 16], sred[0] + sred[1] + sred[2] + sred[3]);
            atomicAdd(&A.sumsEs[(SLOT_E + slot) * 16], sred[4] + sred[5] + sred[6] + sred[7]);
        }
    }
    gridBar(A.bar, b);

    // ---- phase 4 (kE): gate + circular shift + sharpen for this block's 32 rows
    if (t < 64) {
        int head = t >> 5, rr = t & 31;
        int i = b * 32 + rr;
        const float* ee = head ? A.ew : A.er;
        const float* wp = head ? A.wwp : A.wrp;
        const float* sc = A.scal + head * 6;
        float g = sc[1], s0 = sc[2], s1 = sc[3], s2 = sc[4], gamma = sc[5];
        float sE = 0.f;
#pragma unroll
        for (int k = 0; k < SLOT_E; k++) sE += A.sumsEs[(head * SLOT_E + k) * 16];
        float invS = 1.f / sE;
        int im = (i - 1) & (ROWS - 1), ip = (i + 1) & (ROWS - 1);
        float wgm = g * ee[im] * invS + (1.f - g) * wp[im];
        float wg0 = g * ee[i]  * invS + (1.f - g) * wp[i];
        float wgp = g * ee[ip] * invS + (1.f - g) * wp[ip];
        float wt = s0 * wgm + s1 * wg0 + s2 * wgp;
        float pw = powf(wt, gamma);
        spw[t] = pw;                      // stays in LDS for phase 5
        float v = pw;
#pragma unroll
        for (int off = 16; off > 0; off >>= 1) v += __shfl_xor(v, off, 64); // 32-half sums
        if (rr == 0) atomicAdd(&A.sumsPs[(head * SLOT_P + (b & (SLOT_P - 1))) * 16], v);
    }
    gridBar(A.bar, b);

    // ---- phase 5 (kG): normalize, write w_read/w_write, erase+add, read_vec partials
    {
        int r0 = b * 32;
        if (t < 64) {
            int head = t >> 5;
            float s = 0.f;
#pragma unroll
            for (int k = 0; k < SLOT_P; k++) s += A.sumsPs[(head * SLOT_P + k) * 16];
            float inv = 1.f / (s + 1e-8f);
            float vv = spw[t] * inv;
            spw[t] = vv;
            if (head == 0) A.owr[r0 + t] = vv;
            else           A.oww[r0 + (t - 32)] = vv;
        }
        __syncthreads();
        float4 e4 = ((const float4*)A.evec)[t];
        float4 a4 = ((const float4*)A.avec)[t];
        float4 acc = make_float4(0.f, 0.f, 0.f, 0.f);
#pragma unroll 4
        for (int rr = 0; rr < 32; rr++) {
            int r = r0 + rr;
            float wr = spw[rr], ww = spw[32 + rr];
            float4 m = ((const float4*)(A.mem + (size_t)r * COLS))[t];
            vfloat4 o;
            o.x = m.x * (1.f - ww * e4.x) + ww * a4.x;
            o.y = m.y * (1.f - ww * e4.y) + ww * a4.y;
            o.z = m.z * (1.f - ww * e4.z) + ww * a4.z;
            o.w = m.w * (1.f - ww * e4.w) + ww * a4.w;
            __builtin_nontemporal_store(o, ((vfloat4*)(A.memnew + (size_t)r * COLS)) + t);
            acc.x += wr * m.x; acc.y += wr * m.y; acc.z += wr * m.z; acc.w += wr * m.w;
        }
        ((float4*)(A.partials + (size_t)b * COLS))[t] = acc;
    }
    gridBar(A.bar, b);

    // ---- phase 6 (kH): coalesced split-k reduce of partials into readv
    if (b < 128) {
        int ks = b >> 2;                 // 32 k-chunks of 32 partial-blocks each
        int c = (b & 3) * 256 + t;       // consecutive threads -> consecutive columns
        float s = 0.f;
#pragma unroll 8
        for (int k = 0; k < 32; k++) s += A.partials[(size_t)(ks * 32 + k) * COLS + c];
        atomicAdd(&A.readv[c], s);       // 32 adds per column, readv zeroed by kInit
    }
}

extern "C" void kernel_launch(void* const* d_in, const int* in_sizes, int n_in,
                              void* d_out, int out_size, void* d_ws, size_t ws_size,
                              hipStream_t stream) {
    const float* x   = (const float*)d_in[0];
    const float* mem = (const float*)d_in[1];
    const float* Wc  = (const float*)d_in[2];
    const float* bc  = (const float*)d_in[3];
    const float* Wp  = (const float*)d_in[4];
    const float* bp  = (const float*)d_in[5];
    const float* Wo  = (const float*)d_in[6];
    const float* bo  = (const float*)d_in[7];
    const float* rp  = (const float*)d_in[8];
    const float* wrp = (const float*)d_in[9];
    const float* wwp = (const float*)d_in[10];

    float* out    = (float*)d_out;
    float* saida  = out;                                // 256
    float* memnew = out + 256;                          // ROWS*COLS
    float* readv  = out + 256 + (size_t)ROWS * COLS;    // 1024
    float* owr    = readv + COLS;                       // 32768
    float* oww    = owr + ROWS;                         // 32768

    float* ws     = (float*)d_ws;
    float* h      = ws;             // 1024
    float* p      = ws + 1024;      // 4108 (padded)
    float* krn    = ws + 5136;      // 1024
    float* kwn    = ws + 6160;      // 1024
    float* evec   = ws + 7184;      // 1024
    float* avec   = ws + 8208;      // 1024
    float* scal   = ws + 9232;      // 12 (padded to 16)
    float* sumsEs = ws + 9248;      // 2*SLOT_E*16 = 1024
    float* sumsPs = ws + 10272;     // 2*SLOT_P*16 = 512
    int*   bar    = (int*)(ws + 10784);  // 544 ints (padded to 560)
    float* er     = ws + 11344;     // 32768
    float* ew     = er + ROWS;      // 32768
    float* partials = ew + ROWS;    // NBLK*COLS = 1M floats (4 MB)

    KArgs A;
    A.x = x; A.rp = rp; A.Wc = Wc; A.bc = bc; A.Wp = Wp; A.bp = bp;
    A.Wo = Wo; A.bo = bo; A.wrp = wrp; A.wwp = wwp; A.mem = mem;
    A.h = h; A.p = p; A.saida = saida; A.krn = krn; A.kwn = kwn;
    A.evec = evec; A.avec = avec; A.scal = scal; A.sumsEs = sumsEs;
    A.sumsPs = sumsPs; A.bar = bar; A.er = er; A.ew = ew; A.partials = partials;
    A.memnew = memnew; A.readv = readv; A.owr = owr; A.oww = oww;

    kInit<<<dim3(1), dim3(256), 0, stream>>>(bar, sumsEs, sumsPs, readv);
    mega<<<dim3(NBLK), dim3(256), 0, stream>>>(A);
}

// Round 5
// 342.416 us; speedup vs baseline: 2.9729x; 1.9933x over previous
//
#include <hip/hip_runtime.h>
#include <math.h>

#define ROWS 32768
#define COLS 1024
#define HEADSZ 1030      // COLS + 1 + 1 + 3 + 1
#define NPARAMS 4108     // 2*HEADSZ + 2*COLS
#define NBLK 1024        // 4 blocks/CU * 256 CUs (exact-fit, enforced by launch_bounds)
#define SLOT_E 32        // slotted accumulators, cache-line padded (stride 16 floats)
#define SLOT_P 16
// barrier layout (ints, within ws): group g counter at [g*16] (32 groups),
// root counter at [512], generation at [528]; total 544 ints. Counters are
// MONOTONIC (winner = count&31==31, no resets) -> no reset/arrival race.
#define BAR_ROOT 512
#define BAR_GEN  528
#define BAR_INTS 544

typedef float vfloat4 __attribute__((ext_vector_type(4)));

struct KArgs {
    const float *x, *rp, *Wc, *bc, *Wp, *bp, *Wo, *bo, *wrp, *wwp, *mem;
    float *h, *p, *saida, *krn, *kwn, *evec, *avec, *scal, *sumsEs, *sumsPs;
    int   *bar;
    float *er, *ew, *partials, *memnew, *readv, *owr, *oww;
};

__device__ __forceinline__ float softplusf(float x) {
    return fmaxf(x, 0.f) + log1pf(expf(-fabsf(x)));
}
__device__ __forceinline__ float sigmoidf(float x) {
    return 1.f / (1.f + expf(-x));
}
__device__ __forceinline__ float waveReduceSum(float v) {
#pragma unroll
    for (int off = 32; off > 0; off >>= 1) v += __shfl_xor(v, off, 64);
    return v;
}

// Cross-block data path: agent-scope RELAXED atomics = sc0 sc1 accesses that
// write-through / read-through the LLC (coherence point). Never dirty in a
// per-XCD L2 -> the grid barrier needs NO buffer_wbl2 / buffer_inv fences.
__device__ __forceinline__ float ld_g(const float* p) {
    return __hip_atomic_load((const float*)p, __ATOMIC_RELAXED, __HIP_MEMORY_SCOPE_AGENT);
}
__device__ __forceinline__ void st_g(float* p, float v) {
    __hip_atomic_store(p, v, __ATOMIC_RELAXED, __HIP_MEMORY_SCOPE_AGENT);
}

// Fence-free tree grid barrier, monotonic counters.
// __syncthreads() drains vmcnt(0) (compiler-enforced), so every sc1 store of
// this block is at the LLC before the leader's arrive-RMW (also at LLC).
// Winner chain group->root->gen is ordered by fetch-return data dependency.
__device__ __forceinline__ void gridBar(int* bar, int bid) {
    __syncthreads();
    if (threadIdx.x == 0) {
        int* gen = bar + BAR_GEN;
        int g = __hip_atomic_load(gen, __ATOMIC_RELAXED, __HIP_MEMORY_SCOPE_AGENT);
        bool released = false;
        int a = __hip_atomic_fetch_add(bar + (bid >> 5) * 16, 1, __ATOMIC_RELAXED,
                                       __HIP_MEMORY_SCOPE_AGENT);
        if ((a & 31) == 31) {
            int r = __hip_atomic_fetch_add(bar + BAR_ROOT, 1, __ATOMIC_RELAXED,
                                           __HIP_MEMORY_SCOPE_AGENT);
            if ((r & 31) == 31) {
                __hip_atomic_fetch_add(gen, 1, __ATOMIC_RELAXED,
                                       __HIP_MEMORY_SCOPE_AGENT);
                released = true;
            }
        }
        if (!released) {
            int it = 0;
            while (__hip_atomic_load(gen, __ATOMIC_RELAXED,
                                     __HIP_MEMORY_SCOPE_AGENT) == g) {
                __builtin_amdgcn_s_sleep(8);
                if (++it > (1 << 19)) break;  // safety valve: never hang the queue
            }
        }
    }
    __syncthreads();
}

// one output of p/saida: full-1024 dot by one wave (weights plain-cached)
__device__ __forceinline__ void dotOut(const KArgs& A, const float* hl, int o, int lane) {
    bool isP = o < NPARAMS;
    int oo = isP ? o : o - NPARAMS;
    const float* W = isP ? A.Wp : A.Wo;
    const float4* Wr = (const float4*)(W + (size_t)oo * 1024);
    float acc = 0.f;
#pragma unroll
    for (int j = 0; j < 4; j++) {
        float4 w = Wr[lane + 64 * j];
        float4 v = *(const float4*)(hl + lane * 4 + j * 256);
        acc += w.x * v.x + w.y * v.y + w.z * v.z + w.w * v.w;
    }
    acc = waveReduceSum(acc);
    if (lane == 0) {
        if (isP) st_g(A.p + oo, acc + A.bp[oo]);
        else     st_g(A.saida + oo, sigmoidf(acc + A.bo[oo]));
    }
}

// zero barrier state + slotted accumulators + readv (ws is poisoned each launch)
__global__ __launch_bounds__(256) void kInit(int* bar, float* sumsEs,
                                             float* sumsPs, float* readv) {
    int t = threadIdx.x;
    for (int i = t; i < BAR_INTS; i += 256) bar[i] = 0;
    for (int i = t; i < 1024; i += 256) { sumsEs[i] = 0.f; readv[i] = 0.f; }
    for (int i = t; i < 512; i += 256) sumsPs[i] = 0.f;
}

__global__ __launch_bounds__(256, 4) void mega(KArgs A) {
    const int b = blockIdx.x, t = threadIdx.x;
    const int w = t >> 6, lane = t & 63;
    __shared__ float sbuf[1280];   // phase 0: xc, phase 1: h, phase 2: reduction
    __shared__ float spw[64];      // persistent: sharpened weights for this block's 32 rows
    __shared__ float sred[8];

    // ---- phase 0 (kA): h = Wc @ concat(x, read_prev) + bc  (blocks 0..255)
    if (b < 256) {
        for (int i = t; i < 1280; i += 256) sbuf[i] = (i < 256) ? A.x[i] : A.rp[i - 256];
        __syncthreads();
        int o = b * 4 + w;
        const float4* Wr = (const float4*)(A.Wc + (size_t)o * 1280);
        float acc = 0.f;
#pragma unroll
        for (int j = 0; j < 5; j++) {
            float4 wv = Wr[lane + 64 * j];
            float4 v = *(const float4*)(sbuf + lane * 4 + j * 256);
            acc += wv.x * v.x + wv.y * v.y + wv.z * v.z + wv.w * v.w;
        }
        acc = waveReduceSum(acc);
        if (lane == 0) st_g(A.h + o, acc + A.bc[o]);
    }
    gridBar(A.bar, b);

    // ---- phase 1 (kB): 4364 outputs = 1024 blocks * 4 (+ blocks<67 do 4 more)
    {
        for (int i = t; i < 1024; i += 256) sbuf[i] = ld_g(A.h + i);
        __syncthreads();
        dotOut(A, sbuf, b * 4 + w, lane);
        if (b < 67) dotOut(A, sbuf, 4096 + b * 4 + w, lane);
    }
    gridBar(A.bar, b);

    // ---- phase 2 (kC): normalized keys, e/a vectors, scalar params
    if (b < 2) {
        const float* pk = A.p + (b ? HEADSZ : 0);
        float tr[4], ss = 0.f;
#pragma unroll
        for (int j = 0; j < 4; j++) { tr[j] = tanhf(ld_g(pk + t + 256 * j)); ss += tr[j] * tr[j]; }
        sbuf[t] = ss;
        __syncthreads();
        for (int s2 = 128; s2 > 0; s2 >>= 1) {
            if (t < s2) sbuf[t] += sbuf[t + s2];
            __syncthreads();
        }
        float inv = 1.f / fmaxf(sqrtf(sbuf[0]), 1e-12f);
        float* kd = b ? A.kwn : A.krn;
#pragma unroll
        for (int j = 0; j < 4; j++) st_g(kd + t + 256 * j, tr[j] * inv);
    } else if (b == 2) {
#pragma unroll
        for (int j = 0; j < 4; j++) {
            int i = t + 256 * j;
            st_g(A.evec + i, sigmoidf(ld_g(A.p + 2 * HEADSZ + i)));
            st_g(A.avec + i, tanhf(ld_g(A.p + 2 * HEADSZ + COLS + i)));
        }
    } else if (b == 3 && t < 2) {
        int base = t * HEADSZ + COLS;            // 1024 (read) / 2054 (write)
        float beta = softplusf(ld_g(A.p + base));
        float g = sigmoidf(ld_g(A.p + base + 1));
        float s0 = ld_g(A.p + base + 2), s1 = ld_g(A.p + base + 3), s2 = ld_g(A.p + base + 4);
        float mx = fmaxf(s0, fmaxf(s1, s2));
        float e0 = expf(s0 - mx), e1 = expf(s1 - mx), e2 = expf(s2 - mx);
        float invs = 1.f / (e0 + e1 + e2);
        float gamma = softplusf(ld_g(A.p + base + 5)) + 1.f;
        float* sc = A.scal + t * 6;
        st_g(sc + 0, beta); st_g(sc + 1, g);
        st_g(sc + 2, e0 * invs); st_g(sc + 3, e1 * invs); st_g(sc + 4, e2 * invs);
        st_g(sc + 5, gamma);
    }
    gridBar(A.bar, b);

    // ---- phase 3 (kD): sims + row norms -> exp terms + slotted sums (32 rows/block)
    {
        const float beta_r = ld_g(A.scal + 0), beta_w = ld_g(A.scal + 6);
        float4 kr4[4], kw4[4];
#pragma unroll
        for (int j = 0; j < 4; j++) {
            int base = 4 * (lane + 64 * j);
            kr4[j].x = ld_g(A.krn + base);     kr4[j].y = ld_g(A.krn + base + 1);
            kr4[j].z = ld_g(A.krn + base + 2); kr4[j].w = ld_g(A.krn + base + 3);
            kw4[j].x = ld_g(A.kwn + base);     kw4[j].y = ld_g(A.kwn + base + 1);
            kw4[j].z = ld_g(A.kwn + base + 2); kw4[j].w = ld_g(A.kwn + base + 3);
        }
        float lr = 0.f, lw = 0.f;
#pragma unroll
        for (int rr = 0; rr < 8; rr++) {
            int r = b * 32 + w * 8 + rr;
            const float4* row = (const float4*)(A.mem + (size_t)r * COLS);
            float ar = 0.f, aw = 0.f, an = 0.f;
#pragma unroll
            for (int j = 0; j < 4; j++) {
                float4 m = row[lane + 64 * j];
                ar += m.x * kr4[j].x + m.y * kr4[j].y + m.z * kr4[j].z + m.w * kr4[j].w;
                aw += m.x * kw4[j].x + m.y * kw4[j].y + m.z * kw4[j].z + m.w * kw4[j].w;
                an += m.x * m.x + m.y * m.y + m.z * m.z + m.w * m.w;
            }
#pragma unroll
            for (int off = 32; off > 0; off >>= 1) {
                ar += __shfl_xor(ar, off, 64);
                aw += __shfl_xor(aw, off, 64);
                an += __shfl_xor(an, off, 64);
            }
            if (lane == 0) {
                float inv = 1.f / fmaxf(sqrtf(an), 1e-12f);
                // softmax shift by beta (max(beta*sim) <= beta) — exact math
                float vr = expf(beta_r * (ar * inv - 1.f));
                float vw = expf(beta_w * (aw * inv - 1.f));
                st_g(A.er + r, vr); st_g(A.ew + r, vw);
                lr += vr; lw += vw;
            }
        }
        if (lane == 0) { sred[w] = lr; sred[4 + w] = lw; }
        __syncthreads();
        if (t == 0) {
            int slot = b & (SLOT_E - 1);
            atomicAdd(&A.sumsEs[slot * 16], sred[0] + sred[1] + sred[2] + sred[3]);
            atomicAdd(&A.sumsEs[(SLOT_E + slot) * 16], sred[4] + sred[5] + sred[6] + sred[7]);
        }
    }
    gridBar(A.bar, b);

    // ---- phase 4 (kE): gate + circular shift + sharpen for this block's 32 rows
    if (t < 64) {
        int head = t >> 5, rr = t & 31;
        int i = b * 32 + rr;
        const float* ee = head ? A.ew : A.er;
        const float* wp = head ? A.wwp : A.wrp;
        const float* sc = A.scal + head * 6;
        float g = ld_g(sc + 1), s0 = ld_g(sc + 2), s1 = ld_g(sc + 3),
              s2 = ld_g(sc + 4), gamma = ld_g(sc + 5);
        float sE = 0.f;
#pragma unroll
        for (int k = 0; k < SLOT_E; k++) sE += ld_g(A.sumsEs + (head * SLOT_E + k) * 16);
        float invS = 1.f / sE;
        int im = (i - 1) & (ROWS - 1), ip = (i + 1) & (ROWS - 1);
        float wgm = g * ld_g(ee + im) * invS + (1.f - g) * wp[im];
        float wg0 = g * ld_g(ee + i)  * invS + (1.f - g) * wp[i];
        float wgp = g * ld_g(ee + ip) * invS + (1.f - g) * wp[ip];
        float wt = s0 * wgm + s1 * wg0 + s2 * wgp;
        float pw = powf(wt, gamma);
        spw[t] = pw;                      // stays in LDS for phase 5
        float v = pw;
#pragma unroll
        for (int off = 16; off > 0; off >>= 1) v += __shfl_xor(v, off, 64); // 32-half sums
        if (rr == 0) atomicAdd(&A.sumsPs[(head * SLOT_P + (b & (SLOT_P - 1))) * 16], v);
    }
    gridBar(A.bar, b);

    // ---- phase 5 (kG): normalize, write w_read/w_write, erase+add, read_vec partials
    {
        int r0 = b * 32;
        if (t < 64) {
            int head = t >> 5;
            float s = 0.f;
#pragma unroll
            for (int k = 0; k < SLOT_P; k++) s += ld_g(A.sumsPs + (head * SLOT_P + k) * 16);
            float inv = 1.f / (s + 1e-8f);
            float vv = spw[t] * inv;
            spw[t] = vv;
            if (head == 0) A.owr[r0 + t] = vv;
            else           A.oww[r0 + (t - 32)] = vv;
        }
        __syncthreads();
        float4 e4, a4;
        e4.x = ld_g(A.evec + 4 * t);     e4.y = ld_g(A.evec + 4 * t + 1);
        e4.z = ld_g(A.evec + 4 * t + 2); e4.w = ld_g(A.evec + 4 * t + 3);
        a4.x = ld_g(A.avec + 4 * t);     a4.y = ld_g(A.avec + 4 * t + 1);
        a4.z = ld_g(A.avec + 4 * t + 2); a4.w = ld_g(A.avec + 4 * t + 3);
        float4 acc = make_float4(0.f, 0.f, 0.f, 0.f);
#pragma unroll 4
        for (int rr = 0; rr < 32; rr++) {
            int r = r0 + rr;
            float wr = spw[rr], ww = spw[32 + rr];
            float4 m = ((const float4*)(A.mem + (size_t)r * COLS))[t];
            vfloat4 o;
            o.x = m.x * (1.f - ww * e4.x) + ww * a4.x;
            o.y = m.y * (1.f - ww * e4.y) + ww * a4.y;
            o.z = m.z * (1.f - ww * e4.z) + ww * a4.z;
            o.w = m.w * (1.f - ww * e4.w) + ww * a4.w;
            __builtin_nontemporal_store(o, ((vfloat4*)(A.memnew + (size_t)r * COLS)) + t);
            acc.x += wr * m.x; acc.y += wr * m.y; acc.z += wr * m.z; acc.w += wr * m.w;
        }
        float* pb = A.partials + (size_t)b * COLS + 4 * t;
        st_g(pb + 0, acc.x); st_g(pb + 1, acc.y);
        st_g(pb + 2, acc.z); st_g(pb + 3, acc.w);
    }
    gridBar(A.bar, b);

    // ---- phase 6 (kH): coalesced split-k reduce of partials into readv
    if (b < 128) {
        int ks = b >> 2;                 // 32 k-chunks of 32 partial-blocks each
        int c = (b & 3) * 256 + t;       // consecutive threads -> consecutive columns
        float s = 0.f;
#pragma unroll 8
        for (int k = 0; k < 32; k++) s += ld_g(A.partials + (size_t)(ks * 32 + k) * COLS + c);
        atomicAdd(&A.readv[c], s);       // 32 adds per column, readv zeroed by kInit
    }
}

extern "C" void kernel_launch(void* const* d_in, const int* in_sizes, int n_in,
                              void* d_out, int out_size, void* d_ws, size_t ws_size,
                              hipStream_t stream) {
    const float* x   = (const float*)d_in[0];
    const float* mem = (const float*)d_in[1];
    const float* Wc  = (const float*)d_in[2];
    const float* bc  = (const float*)d_in[3];
    const float* Wp  = (const float*)d_in[4];
    const float* bp  = (const float*)d_in[5];
    const float* Wo  = (const float*)d_in[6];
    const float* bo  = (const float*)d_in[7];
    const float* rp  = (const float*)d_in[8];
    const float* wrp = (const float*)d_in[9];
    const float* wwp = (const float*)d_in[10];

    float* out    = (float*)d_out;
    float* saida  = out;                                // 256
    float* memnew = out + 256;                          // ROWS*COLS
    float* readv  = out + 256 + (size_t)ROWS * COLS;    // 1024
    float* owr    = readv + COLS;                       // 32768
    float* oww    = owr + ROWS;                         // 32768

    float* ws     = (float*)d_ws;
    float* h      = ws;             // 1024
    float* p      = ws + 1024;      // 4108 (padded)
    float* krn    = ws + 5136;      // 1024
    float* kwn    = ws + 6160;      // 1024
    float* evec   = ws + 7184;      // 1024
    float* avec   = ws + 8208;      // 1024
    float* scal   = ws + 9232;      // 12 (padded to 16)
    float* sumsEs = ws + 9248;      // 2*SLOT_E*16 = 1024
    float* sumsPs = ws + 10272;     // 2*SLOT_P*16 = 512
    int*   bar    = (int*)(ws + 10784);  // 544 ints (padded to 560)
    float* er     = ws + 11344;     // 32768
    float* ew     = er + ROWS;      // 32768
    float* partials = ew + ROWS;    // NBLK*COLS = 1M floats (4 MB)

    KArgs A;
    A.x = x; A.rp = rp; A.Wc = Wc; A.bc = bc; A.Wp = Wp; A.bp = bp;
    A.Wo = Wo; A.bo = bo; A.wrp = wrp; A.wwp = wwp; A.mem = mem;
    A.h = h; A.p = p; A.saida = saida; A.krn = krn; A.kwn = kwn;
    A.evec = evec; A.avec = avec; A.scal = scal; A.sumsEs = sumsEs;
    A.sumsPs = sumsPs; A.bar = bar; A.er = er; A.ew = ew; A.partials = partials;
    A.memnew = memnew; A.readv = readv; A.owr = owr; A.oww = oww;

    kInit<<<dim3(1), dim3(256), 0, stream>>>(bar, sumsEs, sumsPs, readv);
    mega<<<dim3(NBLK), dim3(256), 0, stream>>>(A);
}